// Round 1
// baseline (174.297 us; speedup 1.0000x reference)
//
#include <hip/hip_runtime.h>
#include <cmath>

// LinearAttention: B=4, T=512, D=192. Chunked linear-attention formulation.
// Chunk C=64, NC=8 chunks/batch. All fp32 (no fp32 MFMA on CDNA4).
#define TB  512
#define DD  192
#define NCH 8
#define CKL 64

static __device__ __forceinline__ float elu1(float v) {
    // elu(x)+1 = x+1 (x>0) else exp(x)
    return v > 0.0f ? v + 1.0f : expf(v);
}

// ---------------------------------------------------------------------------
// K1: qkv = x @ W^T + b  (2048x576, K=192), elu+1 on Q,K; split into Qp/Kp/Vp.
// Tile 128(n) x 64(m), BK=64, 256 threads, 8x4 per thread.
// wsT stored k-major so hot-loop W reads are 16 consecutive float4 (no bank
// conflicts); xs rows assigned as r*16+a so the 4 distinct row addrs per wave
// land on banks {0,4,8,12} (conflict-free).
__global__ __launch_bounds__(256) void k_qkv(
    const float* __restrict__ x, const float* __restrict__ W,
    const float* __restrict__ bias,
    float* __restrict__ Qp, float* __restrict__ Kp, float* __restrict__ Vp)
{
    __shared__ float xs[128][68];
    __shared__ float wsT[64][68];
    const int tid = threadIdx.x;
    const int n0 = blockIdx.x * 128;
    const int m0 = blockIdx.y * 64;
    const int a  = tid >> 4;   // 0..15 (4 distinct per wave)
    const int c  = tid & 15;   // 0..15

    float acc[8][4];
    #pragma unroll
    for (int r = 0; r < 8; ++r)
        #pragma unroll
        for (int s = 0; s < 4; ++s) acc[r][s] = 0.f;

    for (int kb = 0; kb < DD; kb += 64) {
        #pragma unroll
        for (int p = 0; p < 8; ++p) {
            int q = p * 256 + tid;
            int row = q >> 4, c4 = (q & 15) * 4;
            *(float4*)&xs[row][c4] = *(const float4*)&x[(n0 + row) * DD + kb + c4];
        }
        #pragma unroll
        for (int p = 0; p < 4; ++p) {
            int q = p * 256 + tid;
            int row = q >> 4, c4 = (q & 15) * 4;
            float4 wv = *(const float4*)&W[(m0 + row) * DD + kb + c4];
            wsT[c4 + 0][row] = wv.x;
            wsT[c4 + 1][row] = wv.y;
            wsT[c4 + 2][row] = wv.z;
            wsT[c4 + 3][row] = wv.w;
        }
        __syncthreads();
        #pragma unroll
        for (int k = 0; k < 64; k += 4) {
            float wk[4][4];
            #pragma unroll
            for (int j = 0; j < 4; ++j) {
                float4 t4 = *(const float4*)&wsT[k + j][c * 4];
                wk[j][0] = t4.x; wk[j][1] = t4.y; wk[j][2] = t4.z; wk[j][3] = t4.w;
            }
            #pragma unroll
            for (int r = 0; r < 8; ++r) {
                float4 xv = *(const float4*)&xs[r * 16 + a][k];
                #pragma unroll
                for (int s = 0; s < 4; ++s)
                    acc[r][s] += xv.x * wk[0][s] + xv.y * wk[1][s]
                               + xv.z * wk[2][s] + xv.w * wk[3][s];
            }
        }
        __syncthreads();
    }

    const int reg  = m0 / DD;                 // 0:Q 1:K 2:V (tiles never straddle)
    float* dst = (reg == 0) ? Qp : (reg == 1 ? Kp : Vp);
    const int mloc = (m0 % DD) + c * 4;
    #pragma unroll
    for (int r = 0; r < 8; ++r) {
        int n = n0 + r * 16 + a;
        float v0 = acc[r][0] + bias[m0 + c * 4 + 0];
        float v1 = acc[r][1] + bias[m0 + c * 4 + 1];
        float v2 = acc[r][2] + bias[m0 + c * 4 + 2];
        float v3 = acc[r][3] + bias[m0 + c * 4 + 3];
        if (reg < 2) { v0 = elu1(v0); v1 = elu1(v1); v2 = elu1(v2); v3 = elu1(v3); }
        float4 ov = make_float4(v0, v1, v2, v3);
        *(float4*)&dst[n * DD + mloc] = ov;
    }
}

// ---------------------------------------------------------------------------
// K2: per (b,c): M_c[i][j] = sum_t K[t][i]*V[t][j]  (192x192, K-dim 64),
//     z_c[i] = sum_t K[t][i].  Grid (32, 2): jh splits j into halves of 96.
__global__ __launch_bounds__(256) void k_chunksum(
    const float* __restrict__ Kp, const float* __restrict__ Vp,
    float* __restrict__ Mws, float* __restrict__ zws)
{
    __shared__ float Ks[CKL][196];
    const int tid  = threadIdx.x;
    const int bc   = blockIdx.x;     // b*NCH + c
    const int jh   = blockIdx.y;     // 0/1
    const int base = bc * CKL;       // = b*512 + c*64

    #pragma unroll
    for (int p = 0; p < 12; ++p) {
        int q = p * 256 + tid;       // 0..3071 = 64 rows x 48 float4
        int row = q / 48, c4 = (q % 48) * 4;
        *(float4*)&Ks[row][c4] = *(const float4*)&Kp[(base + row) * DD + c4];
    }
    __syncthreads();

    const int ig = tid >> 4, jg = tid & 15;
    const int i0 = ig * 12, j0 = jh * 96 + jg * 6;
    float acc[12][6];
    #pragma unroll
    for (int i = 0; i < 12; ++i)
        #pragma unroll
        for (int j = 0; j < 6; ++j) acc[i][j] = 0.f;

    for (int t = 0; t < CKL; ++t) {
        float kv[12];
        #pragma unroll
        for (int u = 0; u < 3; ++u) {
            float4 t4 = *(const float4*)&Ks[t][i0 + u * 4];
            kv[u*4+0] = t4.x; kv[u*4+1] = t4.y; kv[u*4+2] = t4.z; kv[u*4+3] = t4.w;
        }
        float vv[6];
        #pragma unroll
        for (int u = 0; u < 3; ++u) {
            float2 t2 = *(const float2*)&Vp[(base + t) * DD + j0 + u * 2];
            vv[u*2] = t2.x; vv[u*2+1] = t2.y;
        }
        #pragma unroll
        for (int i = 0; i < 12; ++i)
            #pragma unroll
            for (int j = 0; j < 6; ++j)
                acc[i][j] += kv[i] * vv[j];
    }

    float* Mout = Mws + (size_t)bc * DD * DD;
    #pragma unroll
    for (int i = 0; i < 12; ++i)
        #pragma unroll
        for (int u = 0; u < 3; ++u)
            *(float2*)&Mout[(i0 + i) * DD + j0 + u * 2] =
                make_float2(acc[i][u*2], acc[i][u*2+1]);

    if (jh == 0 && tid < DD) {
        float s = 0.f;
        for (int t = 0; t < CKL; ++t) s += Ks[t][tid];
        zws[bc * DD + tid] = s;
    }
}

// ---------------------------------------------------------------------------
// K3: per (b,c): A = (Q_c K_c^T) causal-masked (64x64, K-dim 192) stored to ws,
//     plus row-sums -> den_local (the intra-chunk part of Q·Z).
__global__ __launch_bounds__(256) void k_scores(
    const float* __restrict__ Qp, const float* __restrict__ Kp,
    float* __restrict__ Aws, float* __restrict__ denws)
{
    __shared__ float Qs[CKL][196];
    const int tid  = threadIdx.x;
    const int bc   = blockIdx.x;
    const int base = bc * CKL;

    #pragma unroll
    for (int p = 0; p < 12; ++p) {
        int q = p * 256 + tid;
        int row = q / 48, c4 = (q % 48) * 4;
        *(float4*)&Qs[row][c4] = *(const float4*)&Qp[(base + row) * DD + c4];
    }
    __syncthreads();

    const int a = tid >> 4, cc = tid & 15;   // t-rows a*4+r, tau-cols cc*4+s
    float acc[4][4];
    #pragma unroll
    for (int r = 0; r < 4; ++r)
        #pragma unroll
        for (int s = 0; s < 4; ++s) acc[r][s] = 0.f;

    for (int k = 0; k < DD; k += 4) {
        float qv[4][4];
        #pragma unroll
        for (int r = 0; r < 4; ++r) {
            float4 t4 = *(const float4*)&Qs[a * 4 + r][k];
            qv[r][0] = t4.x; qv[r][1] = t4.y; qv[r][2] = t4.z; qv[r][3] = t4.w;
        }
        float kv[4][4];
        #pragma unroll
        for (int s = 0; s < 4; ++s) {
            float4 t4 = *(const float4*)&Kp[(base + cc * 4 + s) * DD + k];
            kv[s][0] = t4.x; kv[s][1] = t4.y; kv[s][2] = t4.z; kv[s][3] = t4.w;
        }
        #pragma unroll
        for (int r = 0; r < 4; ++r)
            #pragma unroll
            for (int s = 0; s < 4; ++s)
                acc[r][s] += qv[r][0]*kv[s][0] + qv[r][1]*kv[s][1]
                           + qv[r][2]*kv[s][2] + qv[r][3]*kv[s][3];
    }

    float psum[4];
    #pragma unroll
    for (int r = 0; r < 4; ++r) {
        int trow = a * 4 + r;
        psum[r] = 0.f;
        #pragma unroll
        for (int s = 0; s < 4; ++s) {
            int tau = cc * 4 + s;
            float av = (tau <= trow) ? acc[r][s] : 0.f;  // inclusive causal mask
            Aws[bc * 4096 + trow * 64 + tau] = av;
            psum[r] += av;
        }
    }
    #pragma unroll
    for (int off = 1; off < 16; off <<= 1)
        #pragma unroll
        for (int r = 0; r < 4; ++r)
            psum[r] += __shfl_xor(psum[r], off, 16);
    if (cc == 0) {
        #pragma unroll
        for (int r = 0; r < 4; ++r)
            denws[base + a * 4 + r] = psum[r];
    }
}

// ---------------------------------------------------------------------------
// K4: exclusive prefix over chunk totals: Sb[c] = S0 + sum_{c'<c} M[c'];
//     also writes S_last / Z_last outputs. Elementwise, fully parallel.
__global__ __launch_bounds__(256) void k_prefix(
    const float* __restrict__ Mws, const float* __restrict__ S0,
    const float* __restrict__ zws, const float* __restrict__ Z0,
    float* __restrict__ Sb, float* __restrict__ Zb,
    float* __restrict__ Slast, float* __restrict__ Zlast)
{
    const int w = blockIdx.x;                 // 0..575
    const int b = w / 144;
    const int e = (w % 144) * 256 + threadIdx.x;  // 0..36863
    float acc = S0[b * DD * DD + e];
    #pragma unroll
    for (int cc = 0; cc < NCH; ++cc) {
        Sb[(size_t)(b * NCH + cc) * DD * DD + e] = acc;
        acc += Mws[(size_t)(b * NCH + cc) * DD * DD + e];
    }
    Slast[b * DD * DD + e] = acc;

    if ((w % 144) == 0 && threadIdx.x < DD) {
        const int i = threadIdx.x;
        float za = Z0[b * DD + i];
        #pragma unroll
        for (int cc = 0; cc < NCH; ++cc) {
            Zb[(b * NCH + cc) * DD + i] = za;
            za += zws[(b * NCH + cc) * DD + i];
        }
        Zlast[b * DD + i] = za;
    }
}

// ---------------------------------------------------------------------------
// K5: O[t][l] = sum_tau A[t][tau] V[tau][l] + sum_i Q[t][i] Sb[i][l];
//     den[t] = denws[t] + sum_i Q[t][i] Zb[i] + 1e-5;  out = O/den.
//     Grid (32, 2): th splits the 64 t-rows in halves of 32. 2t x 12l /thread.
__global__ __launch_bounds__(256) void k_output(
    const float* __restrict__ Qp, const float* __restrict__ Vp,
    const float* __restrict__ Aws, const float* __restrict__ denws,
    const float* __restrict__ Sb, const float* __restrict__ Zb,
    float* __restrict__ out)
{
    __shared__ float Qs[32][196];
    const int tid  = threadIdx.x;
    const int bc   = blockIdx.x;
    const int th   = blockIdx.y;
    const int base = bc * CKL;
    const int t0   = th * 32;

    #pragma unroll
    for (int p = 0; p < 6; ++p) {
        int q = p * 256 + tid;       // 32 rows x 48 float4
        int row = q / 48, c4 = (q % 48) * 4;
        *(float4*)&Qs[row][c4] = *(const float4*)&Qp[(base + t0 + row) * DD + c4];
    }
    __syncthreads();

    const int tg = tid >> 4, lg = tid & 15;
    const int l0 = lg * 12;
    float accv[2][12];
    #pragma unroll
    for (int h = 0; h < 2; ++h)
        #pragma unroll
        for (int j = 0; j < 12; ++j) accv[h][j] = 0.f;

    const float* Abase = Aws + bc * 4096;
    const float* Vb    = Vp + (size_t)base * DD;
    for (int tau = 0; tau < CKL; ++tau) {
        float a0 = Abase[(t0 + tg) * 64 + tau];        // masked: 0 for tau>t
        float a1 = Abase[(t0 + tg + 16) * 64 + tau];
        float4 v0 = *(const float4*)&Vb[tau * DD + l0];
        float4 v1 = *(const float4*)&Vb[tau * DD + l0 + 4];
        float4 v2 = *(const float4*)&Vb[tau * DD + l0 + 8];
        float vv[12] = {v0.x,v0.y,v0.z,v0.w, v1.x,v1.y,v1.z,v1.w, v2.x,v2.y,v2.z,v2.w};
        #pragma unroll
        for (int j = 0; j < 12; ++j) {
            accv[0][j] += a0 * vv[j];
            accv[1][j] += a1 * vv[j];
        }
    }

    float dacc0 = 0.f, dacc1 = 0.f;
    const float* Sbc = Sb + (size_t)bc * DD * DD;
    const float* Zbc = Zb + bc * DD;
    for (int i = 0; i < DD; ++i) {
        float q0 = Qs[tg][i], q1 = Qs[tg + 16][i];
        float zb = Zbc[i];
        dacc0 += q0 * zb; dacc1 += q1 * zb;
        float4 s0 = *(const float4*)&Sbc[i * DD + l0];
        float4 s1 = *(const float4*)&Sbc[i * DD + l0 + 4];
        float4 s2 = *(const float4*)&Sbc[i * DD + l0 + 8];
        float sv[12] = {s0.x,s0.y,s0.z,s0.w, s1.x,s1.y,s1.z,s1.w, s2.x,s2.y,s2.z,s2.w};
        #pragma unroll
        for (int j = 0; j < 12; ++j) {
            accv[0][j] += q0 * sv[j];
            accv[1][j] += q1 * sv[j];
        }
    }

    #pragma unroll
    for (int h = 0; h < 2; ++h) {
        int trow = t0 + tg + h * 16;
        float den = denws[base + trow] + (h ? dacc1 : dacc0) + 1e-5f;
        float inv = 1.f / den;
        float* op = out + (size_t)(base + trow) * DD + l0;
        *(float4*)&op[0] = make_float4(accv[h][0]*inv, accv[h][1]*inv,
                                       accv[h][2]*inv, accv[h][3]*inv);
        *(float4*)&op[4] = make_float4(accv[h][4]*inv, accv[h][5]*inv,
                                       accv[h][6]*inv, accv[h][7]*inv);
        *(float4*)&op[8] = make_float4(accv[h][8]*inv, accv[h][9]*inv,
                                       accv[h][10]*inv, accv[h][11]*inv);
    }
}

// ---------------------------------------------------------------------------
extern "C" void kernel_launch(void* const* d_in, const int* in_sizes, int n_in,
                              void* d_out, int out_size, void* d_ws, size_t ws_size,
                              hipStream_t stream)
{
    const float* x  = (const float*)d_in[0];  // (4,512,192)
    const float* W  = (const float*)d_in[1];  // (576,192)
    const float* bb = (const float*)d_in[2];  // (576,)
    const float* S0 = (const float*)d_in[3];  // (4,1,192,192)
    const float* Z0 = (const float*)d_in[4];  // (4,1,192)

    float* out   = (float*)d_out;                       // (4,512,192)
    float* Slast = out + (size_t)4 * TB * DD;           // (4,192*192)
    float* Zlast = Slast + (size_t)4 * DD * DD;         // (4,192)

    // Workspace layout (floats), total ~14.1 MB
    float* ws   = (float*)d_ws;
    float* Qp   = ws;                                   // 4*512*192
    float* Kp   = Qp + (size_t)4 * TB * DD;
    float* Vp   = Kp + (size_t)4 * TB * DD;
    float* Mws  = Vp + (size_t)4 * TB * DD;             // 32 * 192*192
    float* Sbse = Mws + (size_t)4 * NCH * DD * DD;      // 32 * 192*192
    float* zws  = Sbse + (size_t)4 * NCH * DD * DD;     // 32 * 192
    float* Zbse = zws + (size_t)4 * NCH * DD;           // 32 * 192
    float* Aws  = Zbse + (size_t)4 * NCH * DD;          // 32 * 64*64
    float* denw = Aws + (size_t)4 * NCH * CKL * CKL;    // 4*512

    k_qkv     <<<dim3(16, 9), 256, 0, stream>>>(x, W, bb, Qp, Kp, Vp);
    k_chunksum<<<dim3(32, 2), 256, 0, stream>>>(Kp, Vp, Mws, zws);
    k_scores  <<<dim3(32),    256, 0, stream>>>(Qp, Kp, Aws, denw);
    k_prefix  <<<dim3(576),   256, 0, stream>>>(Mws, S0, zws, Z0, Sbse, Zbse, Slast, Zlast);
    k_output  <<<dim3(32, 2), 256, 0, stream>>>(Qp, Vp, Aws, denw, Sbse, Zbse, out);
}

// Round 2
// 121.546 us; speedup vs baseline: 1.4340x; 1.4340x over previous
//
#include <hip/hip_runtime.h>
#include <cmath>

// LinearAttention: B=4, T=512, D=192. Chunked linear-attention formulation.
// Chunk C=64, NC=8 chunks/batch. All fp32 (no fp32 MFMA on CDNA4).
// R1: re-grid all heavy kernels for occupancy (64 -> 192..384 blocks) and
// stage hot-loop operands in LDS (burst loads, not latency-serial).
#define TB  512
#define DD  192
#define NCH 8
#define CKL 64

static __device__ __forceinline__ float elu1(float v) {
    return v > 0.0f ? v + 1.0f : expf(v);
}

// ---------------------------------------------------------------------------
// K1: qkv = x @ W^T + b  (2048x576, K=192), elu+1 on Q,K; split into Qp/Kp/Vp.
// Tile 64(n) x 64(m), BK=64, 256 threads, 4x4 per thread. Grid (32,9)=288.
__global__ __launch_bounds__(256) void k_qkv(
    const float* __restrict__ x, const float* __restrict__ W,
    const float* __restrict__ bias,
    float* __restrict__ Qp, float* __restrict__ Kp, float* __restrict__ Vp)
{
    __shared__ float xs[64][68];
    __shared__ float wsT[64][68];
    const int tid = threadIdx.x;
    const int n0 = blockIdx.x * 64;
    const int m0 = blockIdx.y * 64;
    const int a  = tid >> 4;   // 0..15 (4 distinct per wave)
    const int c  = tid & 15;   // 0..15

    float acc[4][4];
    #pragma unroll
    for (int r = 0; r < 4; ++r)
        #pragma unroll
        for (int s = 0; s < 4; ++s) acc[r][s] = 0.f;

    for (int kb = 0; kb < DD; kb += 64) {
        #pragma unroll
        for (int p = 0; p < 4; ++p) {
            int q = p * 256 + tid;
            int row = q >> 4, c4 = (q & 15) * 4;
            *(float4*)&xs[row][c4] = *(const float4*)&x[(n0 + row) * DD + kb + c4];
        }
        #pragma unroll
        for (int p = 0; p < 4; ++p) {
            int q = p * 256 + tid;
            int row = q >> 4, c4 = (q & 15) * 4;
            float4 wv = *(const float4*)&W[(m0 + row) * DD + kb + c4];
            wsT[c4 + 0][row] = wv.x;
            wsT[c4 + 1][row] = wv.y;
            wsT[c4 + 2][row] = wv.z;
            wsT[c4 + 3][row] = wv.w;
        }
        __syncthreads();
        #pragma unroll
        for (int k = 0; k < 64; k += 4) {
            float wk[4][4];
            #pragma unroll
            for (int j = 0; j < 4; ++j) {
                float4 t4 = *(const float4*)&wsT[k + j][c * 4];
                wk[j][0] = t4.x; wk[j][1] = t4.y; wk[j][2] = t4.z; wk[j][3] = t4.w;
            }
            #pragma unroll
            for (int r = 0; r < 4; ++r) {
                float4 xv = *(const float4*)&xs[r * 16 + a][k];
                #pragma unroll
                for (int s = 0; s < 4; ++s)
                    acc[r][s] += xv.x * wk[0][s] + xv.y * wk[1][s]
                               + xv.z * wk[2][s] + xv.w * wk[3][s];
            }
        }
        __syncthreads();
    }

    const int reg  = m0 / DD;                 // 0:Q 1:K 2:V (64 | 192)
    float* dst = (reg == 0) ? Qp : (reg == 1 ? Kp : Vp);
    const int mloc = (m0 % DD) + c * 4;
    #pragma unroll
    for (int r = 0; r < 4; ++r) {
        int n = n0 + r * 16 + a;
        float v0 = acc[r][0] + bias[m0 + c * 4 + 0];
        float v1 = acc[r][1] + bias[m0 + c * 4 + 1];
        float v2 = acc[r][2] + bias[m0 + c * 4 + 2];
        float v3 = acc[r][3] + bias[m0 + c * 4 + 3];
        if (reg < 2) { v0 = elu1(v0); v1 = elu1(v1); v2 = elu1(v2); v3 = elu1(v3); }
        *(float4*)&dst[n * DD + mloc] = make_float4(v0, v1, v2, v3);
    }
}

// ---------------------------------------------------------------------------
// K2: per (b,c): M_c[i][j] = sum_t K[t][i]*V[t][j] (192x192, red 64),
//     z_c[i] = sum_t K[t][i]. Grid (32, 2 ih, 3 jh) = 192 blocks.
//     Block: 96 i x 64 j; both operand slices staged in LDS.
__global__ __launch_bounds__(256) void k_chunksum(
    const float* __restrict__ Kp, const float* __restrict__ Vp,
    float* __restrict__ Mws, float* __restrict__ zws)
{
    __shared__ float Ks[CKL][100];   // K[t][ih*96 + 0..95]
    __shared__ float Vs[CKL][68];    // V[t][jh*64 + 0..63]
    const int tid  = threadIdx.x;
    const int bc   = blockIdx.x;
    const int ih   = blockIdx.y;     // 0/1
    const int jh   = blockIdx.z;     // 0/1/2
    const int base = bc * CKL;

    #pragma unroll
    for (int p = 0; p < 6; ++p) {
        int q = p * 256 + tid;       // 64 rows x 24 float4
        int row = q / 24, c4 = (q % 24) * 4;
        *(float4*)&Ks[row][c4] = *(const float4*)&Kp[(base + row) * DD + ih * 96 + c4];
    }
    #pragma unroll
    for (int p = 0; p < 4; ++p) {
        int q = p * 256 + tid;       // 64 rows x 16 float4
        int row = q >> 4, c4 = (q & 15) * 4;
        *(float4*)&Vs[row][c4] = *(const float4*)&Vp[(base + row) * DD + jh * 64 + c4];
    }
    __syncthreads();

    const int ig = tid >> 4, jg = tid & 15;
    const int iL = ig * 6;                    // local i within the 96-half
    float acc[6][4];
    #pragma unroll
    for (int i = 0; i < 6; ++i)
        #pragma unroll
        for (int j = 0; j < 4; ++j) acc[i][j] = 0.f;

    #pragma unroll 4
    for (int t = 0; t < CKL; ++t) {
        float4 v = *(const float4*)&Vs[t][jg * 4];
        float2 k0 = *(const float2*)&Ks[t][iL + 0];
        float2 k1 = *(const float2*)&Ks[t][iL + 2];
        float2 k2 = *(const float2*)&Ks[t][iL + 4];
        float kv[6] = {k0.x, k0.y, k1.x, k1.y, k2.x, k2.y};
        #pragma unroll
        for (int i = 0; i < 6; ++i) {
            acc[i][0] += kv[i] * v.x;
            acc[i][1] += kv[i] * v.y;
            acc[i][2] += kv[i] * v.z;
            acc[i][3] += kv[i] * v.w;
        }
    }

    float* Mout = Mws + (size_t)bc * DD * DD;
    const int j0 = jh * 64 + jg * 4;
    #pragma unroll
    for (int i = 0; i < 6; ++i)
        *(float4*)&Mout[(ih * 96 + iL + i) * DD + j0] =
            make_float4(acc[i][0], acc[i][1], acc[i][2], acc[i][3]);

    if (jh == 0 && tid < 96) {
        float s = 0.f;
        #pragma unroll 8
        for (int t = 0; t < CKL; ++t) s += Ks[t][tid];
        zws[bc * DD + ih * 96 + tid] = s;
    }
}

// ---------------------------------------------------------------------------
// K3: per (b,c,tq): A = (Q K^T) causal-masked rows tq*16..+15 (x64 tau, red 192)
//     + row-sums -> denws (intra-chunk part of Q.Z). Grid (32,4)=128 blocks.
__global__ __launch_bounds__(256) void k_scores(
    const float* __restrict__ Qp, const float* __restrict__ Kp,
    float* __restrict__ Aws, float* __restrict__ denws)
{
    __shared__ float Ks[CKL][196];
    __shared__ float Qs[16][196];
    const int tid   = threadIdx.x;
    const int bc    = blockIdx.x;
    const int tq    = blockIdx.y;
    const int base  = bc * CKL;
    const int tbase = tq * 16;

    #pragma unroll
    for (int p = 0; p < 12; ++p) {
        int q = p * 256 + tid;       // 64 rows x 48 float4
        int row = q / 48, c4 = (q % 48) * 4;
        *(float4*)&Ks[row][c4] = *(const float4*)&Kp[(base + row) * DD + c4];
    }
    #pragma unroll
    for (int p = 0; p < 3; ++p) {
        int q = p * 256 + tid;       // 16 rows x 48 float4
        int row = q / 48, c4 = (q % 48) * 4;
        *(float4*)&Qs[row][c4] = *(const float4*)&Qp[(base + tbase + row) * DD + c4];
    }
    __syncthreads();

    const int trow = tid >> 4, tc = tid & 15;
    float acc[4];
    #pragma unroll
    for (int s = 0; s < 4; ++s) acc[s] = 0.f;

    #pragma unroll 4
    for (int k = 0; k < DD; k += 4) {
        float4 qv = *(const float4*)&Qs[trow][k];
        #pragma unroll
        for (int s = 0; s < 4; ++s) {
            float4 kv = *(const float4*)&Ks[tc * 4 + s][k];
            acc[s] += qv.x*kv.x + qv.y*kv.y + qv.z*kv.z + qv.w*kv.w;
        }
    }

    const int tg = tbase + trow;
    float av[4], psum = 0.f;
    #pragma unroll
    for (int s = 0; s < 4; ++s) {
        int tau = tc * 4 + s;
        av[s] = (tau <= tg) ? acc[s] : 0.f;   // inclusive causal mask
        psum += av[s];
    }
    *(float4*)&Aws[bc * 4096 + tg * 64 + tc * 4] = make_float4(av[0], av[1], av[2], av[3]);
    #pragma unroll
    for (int off = 1; off < 16; off <<= 1)
        psum += __shfl_xor(psum, off, 16);
    if (tc == 0) denws[base + tg] = psum;
}

// ---------------------------------------------------------------------------
// K4: exclusive prefix over chunk totals; also writes S_last / Z_last.
__global__ __launch_bounds__(256) void k_prefix(
    const float* __restrict__ Mws, const float* __restrict__ S0,
    const float* __restrict__ zws, const float* __restrict__ Z0,
    float* __restrict__ Sb, float* __restrict__ Zb,
    float* __restrict__ Slast, float* __restrict__ Zlast)
{
    const int w = blockIdx.x;                 // 0..575
    const int b = w / 144;
    const int e = (w % 144) * 256 + threadIdx.x;
    float acc = S0[b * DD * DD + e];
    #pragma unroll
    for (int cc = 0; cc < NCH; ++cc) {
        Sb[(size_t)(b * NCH + cc) * DD * DD + e] = acc;
        acc += Mws[(size_t)(b * NCH + cc) * DD * DD + e];
    }
    Slast[b * DD * DD + e] = acc;

    if ((w % 144) == 0 && threadIdx.x < DD) {
        const int i = threadIdx.x;
        float za = Z0[b * DD + i];
        #pragma unroll
        for (int cc = 0; cc < NCH; ++cc) {
            Zb[(b * NCH + cc) * DD + i] = za;
            za += zws[(b * NCH + cc) * DD + i];
        }
        Zlast[b * DD + i] = za;
    }
}

// ---------------------------------------------------------------------------
// K5: O[t][l] = sum_tau A[t][tau] V[tau][l] + sum_i Q[t][i] Sb[i][l];
//     den[t] = denws[t] + sum_i Q[t][i] Zb[i] + 1e-5; out = O/den.
//     Grid (32 bc, 4 tq, 3 lq) = 384 blocks. Block: 16 t x 64 l.
//     Sb slice (192x64 = 48KB) burst-staged into LDS.
__global__ __launch_bounds__(256) void k_output(
    const float* __restrict__ Qp, const float* __restrict__ Vp,
    const float* __restrict__ Aws, const float* __restrict__ denws,
    const float* __restrict__ Sb, const float* __restrict__ Zb,
    float* __restrict__ out)
{
    __shared__ float Qs[16][196];
    __shared__ float As[16][68];
    __shared__ float Ss[DD][68];
    const int tid   = threadIdx.x;
    const int bc    = blockIdx.x;
    const int tq    = blockIdx.y;
    const int lq    = blockIdx.z;
    const int base  = bc * CKL;
    const int tbase = tq * 16;

    #pragma unroll
    for (int p = 0; p < 3; ++p) {
        int q = p * 256 + tid;
        int row = q / 48, c4 = (q % 48) * 4;
        *(float4*)&Qs[row][c4] = *(const float4*)&Qp[(base + tbase + row) * DD + c4];
    }
    {
        int row = tid >> 4, c4 = (tid & 15) * 4;
        *(float4*)&As[row][c4] =
            *(const float4*)&Aws[bc * 4096 + (tbase + row) * 64 + c4];
    }
    const float* Sbc = Sb + (size_t)bc * DD * DD + lq * 64;
    #pragma unroll
    for (int p = 0; p < 12; ++p) {
        int q = p * 256 + tid;       // 192 rows x 16 float4
        int row = q >> 4, c4 = (q & 15) * 4;
        *(float4*)&Ss[row][c4] = *(const float4*)&Sbc[row * DD + c4];
    }
    __syncthreads();

    const int tg = tid >> 4, lg = tid & 15;
    const int l0 = lq * 64 + lg * 4;
    float ax = 0.f, ay = 0.f, az = 0.f, aw = 0.f, dacc = 0.f;

    const float* Vb = Vp + (size_t)base * DD;
    #pragma unroll 8
    for (int tau = 0; tau < CKL; ++tau) {
        float a = As[tg][tau];
        float4 v = *(const float4*)&Vb[tau * DD + l0];
        ax += a * v.x; ay += a * v.y; az += a * v.z; aw += a * v.w;
    }

    const float* Zbc = Zb + bc * DD;
    #pragma unroll 8
    for (int i = 0; i < DD; ++i) {
        float q = Qs[tg][i];
        float4 s = *(const float4*)&Ss[i][lg * 4];
        ax += q * s.x; ay += q * s.y; az += q * s.z; aw += q * s.w;
        dacc += q * Zbc[i];
    }

    const int trow = tbase + tg;
    float den = denws[base + trow] + dacc + 1e-5f;
    float inv = 1.f / den;
    *(float4*)&out[(size_t)(base + trow) * DD + l0] =
        make_float4(ax * inv, ay * inv, az * inv, aw * inv);
}

// ---------------------------------------------------------------------------
extern "C" void kernel_launch(void* const* d_in, const int* in_sizes, int n_in,
                              void* d_out, int out_size, void* d_ws, size_t ws_size,
                              hipStream_t stream)
{
    const float* x  = (const float*)d_in[0];  // (4,512,192)
    const float* W  = (const float*)d_in[1];  // (576,192)
    const float* bb = (const float*)d_in[2];  // (576,)
    const float* S0 = (const float*)d_in[3];  // (4,1,192,192)
    const float* Z0 = (const float*)d_in[4];  // (4,1,192)

    float* out   = (float*)d_out;                       // (4,512,192)
    float* Slast = out + (size_t)4 * TB * DD;           // (4,192*192)
    float* Zlast = Slast + (size_t)4 * DD * DD;         // (4,192)

    float* ws   = (float*)d_ws;
    float* Qp   = ws;                                   // 4*512*192
    float* Kp   = Qp + (size_t)4 * TB * DD;
    float* Vp   = Kp + (size_t)4 * TB * DD;
    float* Mws  = Vp + (size_t)4 * TB * DD;             // 32 * 192*192
    float* Sbse = Mws + (size_t)4 * NCH * DD * DD;      // 32 * 192*192
    float* zws  = Sbse + (size_t)4 * NCH * DD * DD;     // 32 * 192
    float* Zbse = zws + (size_t)4 * NCH * DD;           // 32 * 192
    float* Aws  = Zbse + (size_t)4 * NCH * DD;          // 32 * 64*64
    float* denw = Aws + (size_t)4 * NCH * CKL * CKL;    // 4*512

    k_qkv     <<<dim3(32, 9),    256, 0, stream>>>(x, W, bb, Qp, Kp, Vp);
    k_chunksum<<<dim3(32, 2, 3), 256, 0, stream>>>(Kp, Vp, Mws, zws);
    k_scores  <<<dim3(32, 4),    256, 0, stream>>>(Qp, Kp, Aws, denw);
    k_prefix  <<<dim3(576),      256, 0, stream>>>(Mws, S0, zws, Z0, Sbse, Zbse, Slast, Zlast);
    k_output  <<<dim3(32, 4, 3), 256, 0, stream>>>(Qp, Vp, Aws, denw, Sbse, Zbse, out);
}

// Round 3
// 99.737 us; speedup vs baseline: 1.7476x; 1.2187x over previous
//
#include <hip/hip_runtime.h>
#include <cmath>

// LinearAttention: B=4, T=512, D=192. Chunked linear-attention formulation.
// Chunk C=64, NC=8 chunks/batch. All fp32 (no fp32 MFMA on CDNA4).
// R3: k_qkv 576 blocks + XOR-swizzled W transpose (kills 8-way staging
// conflicts); fuse chunksum+scores into k_mid (one launch, 320 blocks);
// k_output LDS diet 69->53 KB (3 blocks/CU). 4 launches total.
#define TB  512
#define DD  192
#define NCH 8
#define CKL 64

static __device__ __forceinline__ float elu1(float v) {
    return v > 0.0f ? v + 1.0f : expf(v);
}

// ---------------------------------------------------------------------------
// K1: qkv = x @ W^T + b (2048x576, red 192), elu+1 on Q,K; split Qp/Kp/Vp.
// Tile 32(n) x 64(m), BK=64, 256 threads, 2x4 per thread. Grid (64,9)=576.
// W staged k-major in LDS with fl4-column XOR swizzle: phys_group =
// mgroup ^ ((k>>2)&15). Stores land 2-way (free); reads conflict-free.
__global__ __launch_bounds__(256) void k_qkv(
    const float* __restrict__ x, const float* __restrict__ W,
    const float* __restrict__ bias,
    float* __restrict__ Qp, float* __restrict__ Kp, float* __restrict__ Vp)
{
    __shared__ float xs[32][68];
    __shared__ float wsT[64 * 64];     // [k][m], fl4-swizzled columns
    const int tid = threadIdx.x;
    const int n0 = blockIdx.x * 32;
    const int m0 = blockIdx.y * 64;
    const int a  = tid >> 4;           // 0..15
    const int c  = tid & 15;           // 0..15

    float acc[2][4];
    #pragma unroll
    for (int r = 0; r < 2; ++r)
        #pragma unroll
        for (int s = 0; s < 4; ++s) acc[r][s] = 0.f;

    for (int kb = 0; kb < DD; kb += 64) {
        #pragma unroll
        for (int p = 0; p < 2; ++p) {
            int q = p * 256 + tid;             // 32 rows x 16 fl4
            int row = q >> 4, c4 = (q & 15) * 4;
            *(float4*)&xs[row][c4] = *(const float4*)&x[(n0 + row) * DD + kb + c4];
        }
        #pragma unroll
        for (int p = 0; p < 4; ++p) {
            int q = p * 256 + tid;             // 64 rows x 16 fl4
            int mrow = q >> 4, kidx = q & 15;  // kidx = k fl4-group
            float4 wv = *(const float4*)&W[(m0 + mrow) * DD + kb + kidx * 4];
            int g = (mrow >> 2) ^ kidx;        // swizzled fl4 column group
            int pcol = g * 4 + (mrow & 3);
            wsT[(kidx * 4 + 0) * 64 + pcol] = wv.x;
            wsT[(kidx * 4 + 1) * 64 + pcol] = wv.y;
            wsT[(kidx * 4 + 2) * 64 + pcol] = wv.z;
            wsT[(kidx * 4 + 3) * 64 + pcol] = wv.w;
        }
        __syncthreads();
        #pragma unroll
        for (int kk = 0; kk < 64; kk += 4) {
            float4 xv0 = *(const float4*)&xs[a][kk];
            float4 xv1 = *(const float4*)&xs[16 + a][kk];
            const int g = (c ^ ((kk >> 2) & 15)) * 4;
            float x0[4] = {xv0.x, xv0.y, xv0.z, xv0.w};
            float x1[4] = {xv1.x, xv1.y, xv1.z, xv1.w};
            #pragma unroll
            for (int j = 0; j < 4; ++j) {
                float4 wk = *(const float4*)&wsT[(kk + j) * 64 + g];
                acc[0][0] += x0[j] * wk.x; acc[0][1] += x0[j] * wk.y;
                acc[0][2] += x0[j] * wk.z; acc[0][3] += x0[j] * wk.w;
                acc[1][0] += x1[j] * wk.x; acc[1][1] += x1[j] * wk.y;
                acc[1][2] += x1[j] * wk.z; acc[1][3] += x1[j] * wk.w;
            }
        }
        __syncthreads();
    }

    const int reg  = m0 / DD;              // 0:Q 1:K 2:V (tiles never straddle)
    float* dst = (reg == 0) ? Qp : (reg == 1 ? Kp : Vp);
    const int mloc = (m0 % DD) + c * 4;
    #pragma unroll
    for (int r = 0; r < 2; ++r) {
        int n = n0 + r * 16 + a;
        float v0 = acc[r][0] + bias[m0 + c * 4 + 0];
        float v1 = acc[r][1] + bias[m0 + c * 4 + 1];
        float v2 = acc[r][2] + bias[m0 + c * 4 + 2];
        float v3 = acc[r][3] + bias[m0 + c * 4 + 3];
        if (reg < 2) { v0 = elu1(v0); v1 = elu1(v1); v2 = elu1(v2); v3 = elu1(v3); }
        *(float4*)&dst[n * DD + mloc] = make_float4(v0, v1, v2, v3);
    }
}

// ---------------------------------------------------------------------------
// K2 (fused): grid (32 bc, 10 role).
//   role 0..5: chunksum  M_c[i][j] = sum_t K[t][i]V[t][j], 96i x 64j tile
//              (ih=role/3, jh=role%3); z_c[i] for jh==0.
//   role 6..9: scores    A = (Q K^T) causal rows tq*16..+15, red 192;
//              row-sums -> denws. Q read from global (broadcast, L1).
__global__ __launch_bounds__(256) void k_mid(
    const float* __restrict__ Kp, const float* __restrict__ Vp,
    const float* __restrict__ Qp,
    float* __restrict__ Mws, float* __restrict__ zws,
    float* __restrict__ Aws, float* __restrict__ denws)
{
    __shared__ float sm[64 * 196];     // 50 KB, union of both roles
    const int tid  = threadIdx.x;
    const int bc   = blockIdx.x;
    const int role = blockIdx.y;
    const int base = bc * CKL;

    if (role < 6) {
        // ---- chunksum ----
        const int ih = role / 3, jh = role % 3;
        float (*Ks)[100] = (float (*)[100])sm;          // 64 x 100
        float (*Vs)[68]  = (float (*)[68])(sm + 6400);  // 64 x 68

        #pragma unroll
        for (int p = 0; p < 6; ++p) {
            int q = p * 256 + tid;       // 64 rows x 24 fl4
            int row = q / 24, c4 = (q % 24) * 4;
            *(float4*)&Ks[row][c4] = *(const float4*)&Kp[(base + row) * DD + ih * 96 + c4];
        }
        #pragma unroll
        for (int p = 0; p < 4; ++p) {
            int q = p * 256 + tid;       // 64 rows x 16 fl4
            int row = q >> 4, c4 = (q & 15) * 4;
            *(float4*)&Vs[row][c4] = *(const float4*)&Vp[(base + row) * DD + jh * 64 + c4];
        }
        __syncthreads();

        const int ig = tid >> 4, jg = tid & 15;
        const int iL = ig * 6;
        float acc[6][4];
        #pragma unroll
        for (int i = 0; i < 6; ++i)
            #pragma unroll
            for (int j = 0; j < 4; ++j) acc[i][j] = 0.f;

        #pragma unroll 4
        for (int t = 0; t < CKL; ++t) {
            float4 v = *(const float4*)&Vs[t][jg * 4];
            float2 k0 = *(const float2*)&Ks[t][iL + 0];
            float2 k1 = *(const float2*)&Ks[t][iL + 2];
            float2 k2 = *(const float2*)&Ks[t][iL + 4];
            float kv[6] = {k0.x, k0.y, k1.x, k1.y, k2.x, k2.y};
            #pragma unroll
            for (int i = 0; i < 6; ++i) {
                acc[i][0] += kv[i] * v.x;
                acc[i][1] += kv[i] * v.y;
                acc[i][2] += kv[i] * v.z;
                acc[i][3] += kv[i] * v.w;
            }
        }

        float* Mout = Mws + (size_t)bc * DD * DD;
        const int j0 = jh * 64 + jg * 4;
        #pragma unroll
        for (int i = 0; i < 6; ++i)
            *(float4*)&Mout[(ih * 96 + iL + i) * DD + j0] =
                make_float4(acc[i][0], acc[i][1], acc[i][2], acc[i][3]);

        if (jh == 0 && tid < 96) {
            float s = 0.f;
            #pragma unroll 8
            for (int t = 0; t < CKL; ++t) s += Ks[t][tid];
            zws[bc * DD + ih * 96 + tid] = s;
        }
    } else {
        // ---- scores ----
        const int tq = role - 6;
        const int tbase = tq * 16;
        float (*Ks)[196] = (float (*)[196])sm;          // 64 x 196

        #pragma unroll
        for (int p = 0; p < 12; ++p) {
            int q = p * 256 + tid;       // 64 rows x 48 fl4
            int row = q / 48, c4 = (q % 48) * 4;
            *(float4*)&Ks[row][c4] = *(const float4*)&Kp[(base + row) * DD + c4];
        }
        __syncthreads();

        const int trow = tid >> 4, tc = tid & 15;
        const int tg = tbase + trow;
        const float* Qrow = Qp + (size_t)(base + tg) * DD;
        float acc[4];
        #pragma unroll
        for (int s = 0; s < 4; ++s) acc[s] = 0.f;

        #pragma unroll 4
        for (int k = 0; k < DD; k += 4) {
            float4 qv = *(const float4*)&Qrow[k];      // global, 4-addr broadcast
            #pragma unroll
            for (int s = 0; s < 4; ++s) {
                float4 kv = *(const float4*)&Ks[tc * 4 + s][k];
                acc[s] += qv.x*kv.x + qv.y*kv.y + qv.z*kv.z + qv.w*kv.w;
            }
        }

        float av[4], psum = 0.f;
        #pragma unroll
        for (int s = 0; s < 4; ++s) {
            int tau = tc * 4 + s;
            av[s] = (tau <= tg) ? acc[s] : 0.f;        // inclusive causal mask
            psum += av[s];
        }
        *(float4*)&Aws[bc * 4096 + tg * 64 + tc * 4] =
            make_float4(av[0], av[1], av[2], av[3]);
        #pragma unroll
        for (int off = 1; off < 16; off <<= 1)
            psum += __shfl_xor(psum, off, 16);
        if (tc == 0) denws[base + tg] = psum;
    }
}

// ---------------------------------------------------------------------------
// K3: exclusive prefix over chunk totals; also writes S_last / Z_last.
__global__ __launch_bounds__(256) void k_prefix(
    const float* __restrict__ Mws, const float* __restrict__ S0,
    const float* __restrict__ zws, const float* __restrict__ Z0,
    float* __restrict__ Sb, float* __restrict__ Zb,
    float* __restrict__ Slast, float* __restrict__ Zlast)
{
    const int w = blockIdx.x;                 // 0..575
    const int b = w / 144;
    const int e = (w % 144) * 256 + threadIdx.x;
    float acc = S0[b * DD * DD + e];
    #pragma unroll
    for (int cc = 0; cc < NCH; ++cc) {
        Sb[(size_t)(b * NCH + cc) * DD * DD + e] = acc;
        acc += Mws[(size_t)(b * NCH + cc) * DD * DD + e];
    }
    Slast[b * DD * DD + e] = acc;

    if ((w % 144) == 0 && threadIdx.x < DD) {
        const int i = threadIdx.x;
        float za = Z0[b * DD + i];
        #pragma unroll
        for (int cc = 0; cc < NCH; ++cc) {
            Zb[(b * NCH + cc) * DD + i] = za;
            za += zws[(b * NCH + cc) * DD + i];
        }
        Zlast[b * DD + i] = za;
    }
}

// ---------------------------------------------------------------------------
// K4: O[t][l] = sum_tau A[t][tau] V[tau][l] + sum_i Q[t][i] Sb[i][l];
//     den[t] = denws[t] + sum_i Q[t][i] Zb[i] + 1e-5; out = O/den.
//     Grid (32 bc, 4 tq, 3 lq) = 384 blocks, 16t x 64l per block.
//     LDS: Ss 48 KB + As 4 KB + Zs 0.75 KB = 53 KB -> 3 blocks/CU.
//     Q read from global (4-addr broadcast, L1-resident 12 KB/block).
__global__ __launch_bounds__(256) void k_output(
    const float* __restrict__ Qp, const float* __restrict__ Vp,
    const float* __restrict__ Aws, const float* __restrict__ denws,
    const float* __restrict__ Sb, const float* __restrict__ Zb,
    float* __restrict__ out)
{
    __shared__ float Ss[DD][64];
    __shared__ float As[16][64];
    __shared__ float Zs[DD];
    const int tid   = threadIdx.x;
    const int bc    = blockIdx.x;
    const int tq    = blockIdx.y;
    const int lq    = blockIdx.z;
    const int base  = bc * CKL;
    const int tbase = tq * 16;

    const float* Sbc = Sb + (size_t)bc * DD * DD + lq * 64;
    #pragma unroll
    for (int p = 0; p < 12; ++p) {
        int q = p * 256 + tid;       // 192 rows x 16 fl4
        int row = q >> 4, c4 = (q & 15) * 4;
        *(float4*)&Ss[row][c4] = *(const float4*)&Sbc[row * DD + c4];
    }
    {
        int row = tid >> 4, c4 = (tid & 15) * 4;
        *(float4*)&As[row][c4] =
            *(const float4*)&Aws[bc * 4096 + (tbase + row) * 64 + c4];
    }
    if (tid < 48)
        *(float4*)&Zs[tid * 4] = *(const float4*)&Zb[bc * DD + tid * 4];
    __syncthreads();

    const int tg = tid >> 4, lg = tid & 15;
    const int trow = tbase + tg;
    const int l0 = lq * 64 + lg * 4;
    float ax = 0.f, ay = 0.f, az = 0.f, aw = 0.f, dacc = 0.f;

    const float* Vb = Vp + (size_t)base * DD;
    #pragma unroll 8
    for (int tau = 0; tau < CKL; ++tau) {
        float a = As[tg][tau];
        float4 v = *(const float4*)&Vb[tau * DD + l0];
        ax += a * v.x; ay += a * v.y; az += a * v.z; aw += a * v.w;
    }

    const float* Qrow = Qp + (size_t)(base + trow) * DD;
    #pragma unroll 4
    for (int i = 0; i < DD; i += 4) {
        float4 qv = *(const float4*)&Qrow[i];     // global, 4-addr broadcast
        float4 zv = *(const float4*)&Zs[i];       // LDS broadcast
        dacc += qv.x*zv.x + qv.y*zv.y + qv.z*zv.z + qv.w*zv.w;
        float qq[4] = {qv.x, qv.y, qv.z, qv.w};
        #pragma unroll
        for (int u = 0; u < 4; ++u) {
            float4 s = *(const float4*)&Ss[i + u][lg * 4];
            ax += qq[u] * s.x; ay += qq[u] * s.y;
            az += qq[u] * s.z; aw += qq[u] * s.w;
        }
    }

    float den = denws[base + trow] + dacc + 1e-5f;
    float inv = 1.f / den;
    *(float4*)&out[(size_t)(base + trow) * DD + l0] =
        make_float4(ax * inv, ay * inv, az * inv, aw * inv);
}

// ---------------------------------------------------------------------------
extern "C" void kernel_launch(void* const* d_in, const int* in_sizes, int n_in,
                              void* d_out, int out_size, void* d_ws, size_t ws_size,
                              hipStream_t stream)
{
    const float* x  = (const float*)d_in[0];  // (4,512,192)
    const float* W  = (const float*)d_in[1];  // (576,192)
    const float* bb = (const float*)d_in[2];  // (576,)
    const float* S0 = (const float*)d_in[3];  // (4,1,192,192)
    const float* Z0 = (const float*)d_in[4];  // (4,1,192)

    float* out   = (float*)d_out;                       // (4,512,192)
    float* Slast = out + (size_t)4 * TB * DD;           // (4,192*192)
    float* Zlast = Slast + (size_t)4 * DD * DD;         // (4,192)

    float* ws   = (float*)d_ws;
    float* Qp   = ws;                                   // 4*512*192
    float* Kp   = Qp + (size_t)4 * TB * DD;
    float* Vp   = Kp + (size_t)4 * TB * DD;
    float* Mws  = Vp + (size_t)4 * TB * DD;             // 32 * 192*192
    float* Sbse = Mws + (size_t)4 * NCH * DD * DD;      // 32 * 192*192
    float* zws  = Sbse + (size_t)4 * NCH * DD * DD;     // 32 * 192
    float* Zbse = zws + (size_t)4 * NCH * DD;           // 32 * 192
    float* Aws  = Zbse + (size_t)4 * NCH * DD;          // 32 * 64*64
    float* denw = Aws + (size_t)4 * NCH * CKL * CKL;    // 4*512

    k_qkv   <<<dim3(64, 9),    256, 0, stream>>>(x, W, bb, Qp, Kp, Vp);
    k_mid   <<<dim3(32, 10),   256, 0, stream>>>(Kp, Vp, Qp, Mws, zws, Aws, denw);
    k_prefix<<<dim3(576),      256, 0, stream>>>(Mws, S0, zws, Z0, Sbse, Zbse, Slast, Zlast);
    k_output<<<dim3(32, 4, 3), 256, 0, stream>>>(Qp, Vp, Aws, denw, Sbse, Zbse, out);
}